// Round 8
// baseline (1500.761 us; speedup 1.0000x reference)
//
#include <hip/hip_runtime.h>
#include <cfloat>
#include <climits>
#include <cstdint>

#define NPOINTS 32768
#define NBATCH  2
#define NLEV    4
#define NJOB    5          // 4 voxel levels + 1 point sort
#define PG      16         // point-sort grid
#define PCELLS  (PG*PG*PG)
#define NPB     128
#define NBLK    (NPOINTS / NPB)   // 256

struct BinJob {
  const float* coords;   // [B, N, 3]
  int* cnt; int* start; int* cur;
  float4* sorted;        // [B, N] {x,y,z,bitcast(idx)} in bin order
  int G, ncells, N;
  float invh;
};
struct BinParams { BinJob job[NJOB]; };

struct Level {
  const float4* sorted;  // [B, Nv] coords in bin order, .w = bit-cast original idx
  const int*    start;   // [B, ncells+1]
  int*          idxo;    // [B*Np*3], original-id indexed
  float*        wo;      // [B*Np*3]
  int G, ncells, Nv;
  float h, invh;
};
struct Params { Level lv[NLEV]; };

__device__ __forceinline__ int cell1d(float x, float invh, int G) {
  int c = (int)(x * invh);
  return min(max(c, 0), G - 1);
}

__global__ __launch_bounds__(256) void zero_kernel(int* __restrict__ p, int n)
{
  int i = blockIdx.x * 256 + threadIdx.x;
  if (i < n) p[i] = 0;
}

// ---------------- fused bin counts (all jobs) ----------------
__global__ __launch_bounds__(256) void count_kernel(BinParams prm)
{
  const BinJob J = prm.job[blockIdx.z];
  int v = blockIdx.x * 256 + threadIdx.x;
  int b = blockIdx.y;
  if (v >= J.N) return;
  const float* p = J.coords + ((size_t)b * J.N + v) * 3;
  int cx = cell1d(p[0], J.invh, J.G), cy = cell1d(p[1], J.invh, J.G), cz = cell1d(p[2], J.invh, J.G);
  atomicAdd(&J.cnt[b * J.ncells + (cz * J.G + cy) * J.G + cx], 1);
}

// ---------------- fused exclusive scan (one block per batch x job) ----------------
__global__ __launch_bounds__(1024) void scan_kernel(BinParams prm)
{
  const BinJob J = prm.job[blockIdx.y];
  const int b = blockIdx.x, t = threadIdx.x;
  const int ncells = J.ncells;
  const int* c  = J.cnt + (size_t)b * ncells;
  int* st = J.start + (size_t)b * (ncells + 1);
  int* cu = J.cur + (size_t)b * ncells;
  __shared__ int part[1024];
  const int chunk = (ncells + 1023) / 1024;
  const int lo = t * chunk, hi = min(lo + chunk, ncells);
  int s = 0;
  for (int i = lo; i < hi; ++i) s += c[i];
  part[t] = s;
  __syncthreads();
  for (int off = 1; off < 1024; off <<= 1) {
    int v = (t >= off) ? part[t - off] : 0;
    __syncthreads();
    part[t] += v;
    __syncthreads();
  }
  int base = (t > 0) ? part[t - 1] : 0;
  for (int i = lo; i < hi; ++i) { st[i] = base; cu[i] = base; base += c[i]; }
  if (t == 1023) st[ncells] = part[1023];
}

// ---------------- fused scatter: packed coords+idx into bin order ----------------
__global__ __launch_bounds__(256) void scatter_kernel(BinParams prm)
{
  const BinJob J = prm.job[blockIdx.z];
  int v = blockIdx.x * 256 + threadIdx.x;
  int b = blockIdx.y;
  if (v >= J.N) return;
  const float* p = J.coords + ((size_t)b * J.N + v) * 3;
  float x = p[0], y = p[1], z = p[2];
  int cx = cell1d(x, J.invh, J.G), cy = cell1d(y, J.invh, J.G), cz = cell1d(z, J.invh, J.G);
  int pos = atomicAdd(&J.cur[b * J.ncells + (cz * J.G + cy) * J.G + cx], 1);
  J.sorted[(size_t)b * J.N + pos] = make_float4(x, y, z, __int_as_float(v));
}

// ---- exact 3-NN query: ONE WAVE PER POINT, all levels, zero wave divergence ----
__global__ __launch_bounds__(256) void query_kernel(
    const float4* __restrict__ psorted, Params prm)
{
  const int b = blockIdx.y;
  const int wid  = threadIdx.x >> 6;
  const int lane = threadIdx.x & 63;
  const int sp = blockIdx.x * 4 + wid;          // sorted point slot
  float4 pt = psorted[(size_t)b * NPOINTS + sp];
  const float px = pt.x, py = pt.y, pz = pt.z;
  const int p = __float_as_int(pt.w);           // original point id

  const uint64_t KMAX = ~0ull;

  for (int l = 0; l < NLEV; ++l) {
    const Level L = prm.lv[l];
    const int G = L.G;
    const float h = L.h;
    const int cx = cell1d(px, L.invh, G);
    const int cy = cell1d(py, L.invh, G);
    const int cz = cell1d(pz, L.invh, G);
    const float fx = px - cx * h, fy = py - cy * h, fz = pz - cz * h;
    float m = fminf(fminf(fminf(fx, h - fx), fminf(fy, h - fy)), fminf(fz, h - fz));
    m = fmaxf(m, 0.f);

    const int* start     = L.start  + (size_t)b * (L.ncells + 1);
    const float4* sorted = L.sorted + (size_t)b * L.Nv;

    uint64_t t0 = KMAX, t1 = KMAX, t2 = KMAX;
    auto ins3 = [&](uint64_t k) {
      if (k < t2) {
        if (k < t1) { t2 = t1; if (k < t0) { t1 = t0; t0 = k; } else t1 = k; }
        else t2 = k;
      }
    };
    auto evalk = [&](int k) {
      float4 vv = sorted[k];
      int vi = __float_as_int(vv.w);
      // exact reference arithmetic: individually-rounded squares, (x2+y2)+z2
      float dx = px - vv.x, dy = py - vv.y, dz = pz - vv.z;
      float d2 = __fadd_rn(__fadd_rn(__fmul_rn(dx, dx), __fmul_rn(dy, dy)),
                           __fmul_rn(dz, dz));
      uint64_t key = ((uint64_t)__float_as_uint(d2) << 32) | (uint32_t)vi;
      ins3(key);
    };
    auto wave_merge = [&]() {
      for (int mask = 1; mask < 64; mask <<= 1) {
        uint32_t a0 = __shfl_xor((unsigned)(t0 & 0xffffffffu), mask);
        uint32_t a1 = __shfl_xor((unsigned)(t0 >> 32), mask);
        uint32_t b0_ = __shfl_xor((unsigned)(t1 & 0xffffffffu), mask);
        uint32_t b1_ = __shfl_xor((unsigned)(t1 >> 32), mask);
        uint32_t c0 = __shfl_xor((unsigned)(t2 & 0xffffffffu), mask);
        uint32_t c1 = __shfl_xor((unsigned)(t2 >> 32), mask);
        ins3(((uint64_t)a1 << 32) | a0);
        ins3(((uint64_t)b1_ << 32) | b0_);
        ins3(((uint64_t)c1 << 32) | c0);
      }
    };

    // lanes 0..8 own the 9 x-rows of the 3x3x3 block (independent bound loads)
    int ks = 0, cnt = 0;
    if (lane < 9) {
      int iz = cz + lane / 3 - 1, iy = cy + lane % 3 - 1;
      if (iz >= 0 && iz < G && iy >= 0 && iy < G) {
        int x0 = max(cx - 1, 0), x1 = min(cx + 1, G - 1);
        int row = (iz * G + iy) * G;
        ks  = start[row + x0];
        cnt = start[row + x1 + 1] - ks;
      }
    }
    int c[9], kb[9];
    #pragma unroll
    for (int r = 0; r < 9; ++r) { c[r] = __shfl(cnt, r); kb[r] = __shfl(ks, r); }
    int M = 0;
    #pragma unroll
    for (int r = 0; r < 9; ++r) M += c[r];

    // flattened candidate loop (wave-uniform bound, coalesced segment reads)
    for (int j = lane; j < M; j += 64) {
      int rem = j, addr = -1;
      #pragma unroll
      for (int r = 0; r < 9; ++r) {
        if (addr < 0) {
          if (rem < c[r]) addr = kb[r] + rem;
          else rem -= c[r];
        }
      }
      evalk(addr);
    }
    wave_merge();

    // stop bound: ball(h+m) is contained in the 3x3x3 block
    float d2_3 = __uint_as_float((uint32_t)(t2 >> 32));
    float dmin = h + m;
    if (!(dmin * dmin * 0.99999f > d2_3)) {
      // ultra-rare exact fallback: uniform whole-wave rescan of the level
      t0 = t1 = t2 = KMAX;
      for (int k = lane; k < L.Nv; k += 64) evalk(k);
      wave_merge();
    }

    if (lane == 0) {
      float d20 = __uint_as_float((uint32_t)(t0 >> 32));
      float d21 = __uint_as_float((uint32_t)(t1 >> 32));
      float d22 = __uint_as_float((uint32_t)(t2 >> 32));
      float w0 = 1.0f / (sqrtf(d20) + 1e-8f);
      float w1 = 1.0f / (sqrtf(d21) + 1e-8f);
      float w2 = 1.0f / (sqrtf(d22) + 1e-8f);
      float ws = (w0 + w1) + w2;
      size_t o = ((size_t)b * NPOINTS + p) * 3;
      L.idxo[o] = (int)(uint32_t)t0; L.idxo[o + 1] = (int)(uint32_t)t1; L.idxo[o + 2] = (int)(uint32_t)t2;
      L.wo[o] = w0 / ws; L.wo[o + 1] = w1 / ws; L.wo[o + 2] = w2 / ws;
    }
  }
}

// ---------------- Gather-interp (float4) + per-block channel partial sums ----------------
template <int C, int BDIM>
__global__ __launch_bounds__(BDIM) void interp_kernel(
    const float* __restrict__ voxf, const int* __restrict__ idxo,
    const float* __restrict__ wo, float* __restrict__ out,
    float* __restrict__ psum, float* __restrict__ psq, int Nv)
{
  constexpr int C4 = C / 4;
  constexpr int R  = BDIM / C4;
  const int b = blockIdx.y, blk = blockIdx.x;
  const int tid = threadIdx.x;
  const int r = tid / C4, c4 = tid - r * C4;
  const float4* fb = (const float4*)(voxf + (size_t)b * Nv * C);
  float4* ob = (float4*)(out + (size_t)b * NPOINTS * C);
  const int p0 = blk * NPB;

  float4 s = make_float4(0, 0, 0, 0), q = make_float4(0, 0, 0, 0);
  for (int p = p0 + r; p < p0 + NPB; p += R) {
    size_t pg = ((size_t)b * NPOINTS + p) * 3;
    int   ia = idxo[pg], ib = idxo[pg + 1], ic = idxo[pg + 2];
    float wa = wo[pg],   wb = wo[pg + 1],   wc = wo[pg + 2];
    float4 fa = fb[(size_t)ia * C4 + c4];
    float4 f2 = fb[(size_t)ib * C4 + c4];
    float4 fc = fb[(size_t)ic * C4 + c4];
    float4 o;
    o.x = wa * fa.x + wb * f2.x + wc * fc.x;
    o.y = wa * fa.y + wb * f2.y + wc * fc.y;
    o.z = wa * fa.z + wb * f2.z + wc * fc.z;
    o.w = wa * fa.w + wb * f2.w + wc * fc.w;
    ob[(size_t)p * C4 + c4] = o;
    s.x += o.x; s.y += o.y; s.z += o.z; s.w += o.w;
    q.x += o.x * o.x; q.y += o.y * o.y; q.z += o.z * o.z; q.w += o.w * o.w;
  }

  __shared__ float4 ls[BDIM];
  ls[tid] = s;
  __syncthreads();
  if (r == 0) {
    float4 tot = s;
    #pragma unroll
    for (int rr = 1; rr < R; ++rr) {
      float4 v = ls[c4 + rr * C4];
      tot.x += v.x; tot.y += v.y; tot.z += v.z; tot.w += v.w;
    }
    ((float4*)psum)[((size_t)b * NBLK + blk) * C4 + c4] = tot;
  }
  __syncthreads();
  ls[tid] = q;
  __syncthreads();
  if (r == 0) {
    float4 tot = q;
    #pragma unroll
    for (int rr = 1; rr < R; ++rr) {
      float4 v = ls[c4 + rr * C4];
      tot.x += v.x; tot.y += v.y; tot.z += v.z; tot.w += v.w;
    }
    ((float4*)psq)[((size_t)b * NBLK + blk) * C4 + c4] = tot;
  }
}

// ---------------- BN stats (parallel reduce over NBLK partials) ----------------
__global__ __launch_bounds__(256) void bn_stats_kernel(
    const float* __restrict__ psum, const float* __restrict__ psq,
    const float* __restrict__ gamma, const float* __restrict__ beta,
    float* __restrict__ scale, float* __restrict__ shift, int C, float invN)
{
  const int c = blockIdx.x, b = blockIdx.y, t = threadIdx.x;
  float s = 0.f, q = 0.f;
  for (int k = t; k < NBLK; k += 256) {
    s += psum[((size_t)b * NBLK + k) * C + c];
    q += psq[((size_t)b * NBLK + k) * C + c];
  }
  __shared__ float ss[256], qs[256];
  ss[t] = s; qs[t] = q;
  __syncthreads();
  for (int o = 128; o > 0; o >>= 1) {
    if (t < o) { ss[t] += ss[t + o]; qs[t] += qs[t + o]; }
    __syncthreads();
  }
  if (t == 0) {
    float mu  = ss[0] * invN;
    float var = fmaxf(qs[0] * invN - mu * mu, 0.f);
    float sc  = gamma[c] * rsqrtf(var + 1e-5f);
    scale[b * C + c] = sc;
    shift[b * C + c] = beta[c] - mu * sc;
  }
}

// ---------------- In-place normalize (float4) ----------------
__global__ __launch_bounds__(256) void bn_apply_kernel(
    float* __restrict__ out, const float* __restrict__ scale,
    const float* __restrict__ shift, int C, int NpC)
{
  const int e = blockIdx.x * 256 + threadIdx.x;
  const int npc4 = NpC >> 2, c4n = C >> 2;
  const int b = e / npc4;
  const int rem = e - b * npc4;
  const int c4 = rem % c4n;
  float4 v  = ((float4*)out)[e];
  float4 sc = ((const float4*)scale)[b * c4n + c4];
  float4 sh = ((const float4*)shift)[b * c4n + c4];
  v.x = fmaf(v.x, sc.x, sh.x);
  v.y = fmaf(v.y, sc.y, sh.y);
  v.z = fmaf(v.z, sc.z, sh.z);
  v.w = fmaf(v.w, sc.w, sh.w);
  ((float4*)out)[e] = v;
}

// ---------------- Host launch ----------------
extern "C" void kernel_launch(void* const* d_in, const int* in_sizes, int n_in,
                              void* d_out, int out_size, void* d_ws, size_t ws_size,
                              hipStream_t stream)
{
  const float* ptc = (const float*)d_in[0];
  static const int    Cs[4]     = {256, 128, 96, 96};
  static const int    Nvs[4]    = {2048, 6144, 16384, 32768};
  static const int    Gs[4]     = {10, 14, 18, 22};   // ~2-3 voxels/cell
  static const size_t outOff[4] = {0, 16777216, 25165824, 31457280};

  // ---- workspace carve ----
  size_t off = 0;
  auto carve = [&](size_t bytes) {
    off = (off + 255) & ~(size_t)255;
    size_t o = off; off += bytes; return o;
  };
  char* w = (char*)d_ws;

  int nc[NJOB];
  for (int l = 0; l < 4; ++l) nc[l] = Gs[l] * Gs[l] * Gs[l];
  nc[4] = PCELLS;
  int Ns[NJOB] = {Nvs[0], Nvs[1], Nvs[2], Nvs[3], NPOINTS};
  int Gj[NJOB] = {Gs[0], Gs[1], Gs[2], Gs[3], PG};

  // contiguous counter block (zeroed with one launch)
  int totcnt = 0;
  for (int j = 0; j < NJOB; ++j) totcnt += nc[j];
  int* cntbase = (int*)(w + carve((size_t)NBATCH * totcnt * 4));

  float4* sortedj[NJOB]; int* cntj[NJOB]; int* sttj[NJOB]; int* curj[NJOB];
  {
    int acc = 0;
    for (int j = 0; j < NJOB; ++j) {
      cntj[j] = cntbase + (size_t)NBATCH * acc;
      acc += nc[j];
    }
  }
  for (int j = 0; j < NJOB; ++j) {
    sortedj[j] = (float4*)(w + carve((size_t)NBATCH * Ns[j] * 16));
    sttj[j]    = (int*)   (w + carve((size_t)NBATCH * (nc[j] + 1) * 4));
    curj[j]    = (int*)   (w + carve((size_t)NBATCH * nc[j] * 4));
  }
  int*   idxo  = (int*)  (w + carve((size_t)NLEV * NBATCH * NPOINTS * 3 * 4));
  float* wo    = (float*)(w + carve((size_t)NLEV * NBATCH * NPOINTS * 3 * 4));
  float* psum  = (float*)(w + carve((size_t)NBATCH * NBLK * 256 * 4));
  float* psq   = (float*)(w + carve((size_t)NBATCH * NBLK * 256 * 4));
  float* scale = (float*)(w + carve((size_t)NBATCH * 256 * 4));
  float* shift = (float*)(w + carve((size_t)NBATCH * 256 * 4));

  BinParams bp;
  for (int j = 0; j < NJOB; ++j) {
    BinJob& J = bp.job[j];
    J.coords = (j < 4) ? (const float*)d_in[1 + 4 * j] : ptc;
    J.cnt = cntj[j]; J.start = sttj[j]; J.cur = curj[j]; J.sorted = sortedj[j];
    J.G = Gj[j]; J.ncells = nc[j]; J.N = Ns[j];
    J.invh = Gj[j] / 50.0f;
  }

  Params prm;
  for (int l = 0; l < 4; ++l) {
    Level& L = prm.lv[l];
    L.sorted = sortedj[l]; L.start = sttj[l];
    L.idxo = idxo + (size_t)l * NBATCH * NPOINTS * 3;
    L.wo   = wo   + (size_t)l * NBATCH * NPOINTS * 3;
    L.G = Gs[l]; L.ncells = nc[l]; L.Nv = Nvs[l];
    L.h = 50.0f / Gs[l]; L.invh = Gs[l] / 50.0f;
  }

  // ---- fused binning ----
  const int zn = NBATCH * totcnt;
  zero_kernel<<<(zn + 255) / 256, 256, 0, stream>>>(cntbase, zn);
  count_kernel<<<dim3((NPOINTS + 255) / 256, NBATCH, NJOB), 256, 0, stream>>>(bp);
  scan_kernel<<<dim3(NBATCH, NJOB), 1024, 0, stream>>>(bp);
  scatter_kernel<<<dim3((NPOINTS + 255) / 256, NBATCH, NJOB), 256, 0, stream>>>(bp);

  // ---- exact 3-NN query: one wave per point, loop over levels ----
  query_kernel<<<dim3(NPOINTS / 4, NBATCH), 256, 0, stream>>>(sortedj[4], prm);

  // ---- per-level: interp(+stats) -> BN stats -> in-place apply ----
  for (int l = 0; l < 4; ++l) {
    const float* voxf  = (const float*)d_in[2 + 4 * l];
    const float* gamma = (const float*)d_in[3 + 4 * l];
    const float* beta  = (const float*)d_in[4 + 4 * l];
    const int C = Cs[l], Nv = Nvs[l];
    float* outl = (float*)d_out + outOff[l];
    const int* idl = idxo + (size_t)l * NBATCH * NPOINTS * 3;
    const float* wl = wo  + (size_t)l * NBATCH * NPOINTS * 3;

    if (C == 256)
      interp_kernel<256, 256><<<dim3(NBLK, NBATCH), 256, 0, stream>>>(
          voxf, idl, wl, outl, psum, psq, Nv);
    else if (C == 128)
      interp_kernel<128, 256><<<dim3(NBLK, NBATCH), 256, 0, stream>>>(
          voxf, idl, wl, outl, psum, psq, Nv);
    else
      interp_kernel<96, 240><<<dim3(NBLK, NBATCH), 240, 0, stream>>>(
          voxf, idl, wl, outl, psum, psq, Nv);

    bn_stats_kernel<<<dim3(C, NBATCH), 256, 0, stream>>>(
        psum, psq, gamma, beta, scale, shift, C, 1.0f / NPOINTS);

    const int n4 = NBATCH * NPOINTS * C / 4;
    bn_apply_kernel<<<n4 / 256, 256, 0, stream>>>(
        (float*)outl, scale, shift, C, NPOINTS * C);
  }
}

// Round 10
// 514.696 us; speedup vs baseline: 2.9158x; 2.9158x over previous
//
#include <hip/hip_runtime.h>
#include <cfloat>
#include <climits>
#include <cstdint>

#define NPOINTS 32768
#define NBATCH  2
#define NLEV    4
#define NJOB    5          // 4 voxel levels + 1 point sort
#define PG      16         // point-sort grid
#define PCELLS  (PG*PG*PG)
#define NPB     128
#define NBLK    (NPOINTS / NPB)   // 256

struct BinJob {
  const float* coords;   // [B, N, 3]
  int* cnt; int* start; int* cur;
  float4* sorted;        // [B, N] {x,y,z,bitcast(idx)} in bin order
  int G, ncells, N;
  float invh;
};
struct BinParams { BinJob job[NJOB]; };

struct Level {
  const float4* sorted;  // [B, Nv] coords in bin order, .w = bit-cast original idx
  const int*    start;   // [B, ncells+1]
  int*          idxo;    // [B*Np*3], original-id indexed
  float*        wo;      // [B*Np*3]
  int G, ncells, Nv;
  float h, invh;
};
struct Params { Level lv[NLEV]; };

__device__ __forceinline__ int cell1d(float x, float invh, int G) {
  int c = (int)(x * invh);
  return min(max(c, 0), G - 1);
}

__global__ __launch_bounds__(256) void zero_kernel(int* __restrict__ p, int n)
{
  int i = blockIdx.x * 256 + threadIdx.x;
  if (i < n) p[i] = 0;
}

// ---------------- fused bin counts (all jobs) ----------------
__global__ __launch_bounds__(256) void count_kernel(BinParams prm)
{
  const BinJob J = prm.job[blockIdx.z];
  int v = blockIdx.x * 256 + threadIdx.x;
  int b = blockIdx.y;
  if (v >= J.N) return;
  const float* p = J.coords + ((size_t)b * J.N + v) * 3;
  int cx = cell1d(p[0], J.invh, J.G), cy = cell1d(p[1], J.invh, J.G), cz = cell1d(p[2], J.invh, J.G);
  atomicAdd(&J.cnt[b * J.ncells + (cz * J.G + cy) * J.G + cx], 1);
}

// ---------------- fused exclusive scan (one block per batch x job) ----------------
__global__ __launch_bounds__(1024) void scan_kernel(BinParams prm)
{
  const BinJob J = prm.job[blockIdx.y];
  const int b = blockIdx.x, t = threadIdx.x;
  const int ncells = J.ncells;
  const int* c  = J.cnt + (size_t)b * ncells;
  int* st = J.start + (size_t)b * (ncells + 1);
  int* cu = J.cur + (size_t)b * ncells;
  __shared__ int part[1024];
  const int chunk = (ncells + 1023) / 1024;
  const int lo = t * chunk, hi = min(lo + chunk, ncells);
  int s = 0;
  for (int i = lo; i < hi; ++i) s += c[i];
  part[t] = s;
  __syncthreads();
  for (int off = 1; off < 1024; off <<= 1) {
    int v = (t >= off) ? part[t - off] : 0;
    __syncthreads();
    part[t] += v;
    __syncthreads();
  }
  int base = (t > 0) ? part[t - 1] : 0;
  for (int i = lo; i < hi; ++i) { st[i] = base; cu[i] = base; base += c[i]; }
  if (t == 1023) st[ncells] = part[1023];
}

// ---------------- fused scatter: packed coords+idx into bin order ----------------
__global__ __launch_bounds__(256) void scatter_kernel(BinParams prm)
{
  const BinJob J = prm.job[blockIdx.z];
  int v = blockIdx.x * 256 + threadIdx.x;
  int b = blockIdx.y;
  if (v >= J.N) return;
  const float* p = J.coords + ((size_t)b * J.N + v) * 3;
  float x = p[0], y = p[1], z = p[2];
  int cx = cell1d(x, J.invh, J.G), cy = cell1d(y, J.invh, J.G), cz = cell1d(z, J.invh, J.G);
  int pos = atomicAdd(&J.cur[b * J.ncells + (cz * J.G + cy) * J.G + cx], 1);
  J.sorted[(size_t)b * J.N + pos] = make_float4(x, y, z, __int_as_float(v));
}

// ---- exact 3-NN query: 16 lanes per point, 32-bit shuffles only (proven primitives) ----
__global__ __launch_bounds__(256) void query_kernel(
    const float4* __restrict__ psorted, Params prm)
{
  const int l = blockIdx.y, b = blockIdx.z;
  const Level L = prm.lv[l];
  const int tid = threadIdx.x;
  const int ln = tid & 15;                       // lane within 16-group
  const int gbase = (tid & 63) & ~15;            // group base lane within wave
  const int sp = blockIdx.x * 16 + (tid >> 4);   // sorted point slot
  float4 pt = psorted[(size_t)b * NPOINTS + sp];
  const float px = pt.x, py = pt.y, pz = pt.z;
  const int p = __float_as_int(pt.w);            // original point id
  const int G = L.G;
  const float h = L.h;

  const int cx = cell1d(px, L.invh, G);
  const int cy = cell1d(py, L.invh, G);
  const int cz = cell1d(pz, L.invh, G);
  const float fx = px - cx * h, fy = py - cy * h, fz = pz - cz * h;
  float m = fminf(fminf(fminf(fx, h - fx), fminf(fy, h - fy)), fminf(fz, h - fz));
  m = fmaxf(m, 0.f);

  const int* start     = L.start  + (size_t)b * (L.ncells + 1);
  const float4* sorted = L.sorted + (size_t)b * L.Nv;

  float b0 = FLT_MAX, b1 = FLT_MAX, b2 = FLT_MAX;
  int   i0 = INT_MAX, i1 = INT_MAX, i2 = INT_MAX;

  auto ins = [&](float d2, int vi) {             // lex (d2, idx) — R5/R7-proven
    if (d2 < b2 || (d2 == b2 && vi < i2)) {
      if (d2 < b1 || (d2 == b1 && vi < i1)) {
        b2 = b1; i2 = i1;
        if (d2 < b0 || (d2 == b0 && vi < i0)) { b1 = b0; i1 = i0; b0 = d2; i0 = vi; }
        else                                  { b1 = d2; i1 = vi; }
      } else { b2 = d2; i2 = vi; }
    }
  };
  auto evalk = [&](int k) {
    float4 vv = sorted[k];
    int vi = __float_as_int(vv.w);
    // exact reference arithmetic: individually-rounded squares, (x2+y2)+z2
    float dx = px - vv.x, dy = py - vv.y, dz = pz - vv.z;
    float d2 = __fadd_rn(__fadd_rn(__fmul_rn(dx, dx), __fmul_rn(dy, dy)),
                         __fmul_rn(dz, dz));
    ins(d2, vi);
  };
  auto gmin = [&](float v) {                     // group-wide min (32-bit float shfl)
    #pragma unroll
    for (int mask = 1; mask < 16; mask <<= 1)
      v = fminf(v, __shfl_xor(v, mask));
    return v;
  };

  // ---- Phase 1: 3x3x3 block; lanes 0..8 issue the 9 row-bound loads in parallel ----
  int ks = 0, rc = 0;
  if (ln < 9) {
    int iz = cz + ln / 3 - 1, iy = cy + ln % 3 - 1;
    if (iz >= 0 && iz < G && iy >= 0 && iy < G) {
      int x0 = max(cx - 1, 0), x1 = min(cx + 1, G - 1);
      int row = (iz * G + iy) * G;
      ks = start[row + x0];
      rc = start[row + x1 + 1] - ks;
    }
  }
  #pragma unroll
  for (int r = 0; r < 9; ++r) {
    int rk = __shfl(ks, gbase + r);              // absolute-lane 32-bit broadcast
    int rn = __shfl(rc, gbase + r);
    for (int k = rk + ln; k < rk + rn; k += 16) evalk(k);
  }

  // ---- Phase 2: rare ring tail from rho=2 (ball(h+m) contained in block) ----
  {
    float bm = gmin(b2);                         // bm >= true group b2 -> conservative
    float dmin = h + m;
    if (!(dmin * dmin * 0.99999f > bm)) {
      const int rmax = max(max(cx, G - 1 - cx), max(max(cy, G - 1 - cy), max(cz, G - 1 - cz)));
      for (int rho = 2; rho <= rmax; ++rho) {
        bm = gmin(b2);
        float dmn = fmaxf((rho - 1) * h + m, 0.f);
        if (dmn * dmn * 0.99999f > bm) break;    // conservative exact prune
        const int z0 = max(cz - rho, 0), z1 = min(cz + rho, G - 1);
        const int y0 = max(cy - rho, 0), y1 = min(cy + rho, G - 1);
        for (int iz = z0; iz <= z1; ++iz) {
          const int adz = abs(iz - cz);
          for (int iy = y0; iy <= y1; ++iy) {
            const int ady = max(adz, abs(iy - cy));
            const int row = (iz * G + iy) * G;
            if (ady == rho) {
              const int xa = max(cx - rho, 0), xb = min(cx + rho, G - 1);
              int a = start[row + xa], e = start[row + xb + 1];
              for (int k = a + ln; k < e; k += 16) evalk(k);
            } else {
              const int xl = cx - rho, xr = cx + rho;
              if (xl >= 0) {
                int a = start[row + xl], e = start[row + xl + 1];
                for (int k = a + ln; k < e; k += 16) evalk(k);
              }
              if (xr <= G - 1) {
                int a = start[row + xr], e = start[row + xr + 1];
                for (int k = a + ln; k < e; k += 16) evalk(k);
              }
            }
          }
        }
      }
    }
  }

  // ---- final merge: butterfly over the 16-lane group, 32-bit pair shuffles (R7-proven) ----
  #pragma unroll
  for (int mask = 1; mask <= 8; mask <<= 1) {
    float c0 = __shfl_xor(b0, mask), c1 = __shfl_xor(b1, mask), c2 = __shfl_xor(b2, mask);
    int   j0 = __shfl_xor(i0, mask), j1 = __shfl_xor(i1, mask), j2 = __shfl_xor(i2, mask);
    ins(c0, j0); ins(c1, j1); ins(c2, j2);
  }

  if (ln == 0) {
    float w0 = 1.0f / (sqrtf(b0) + 1e-8f);
    float w1 = 1.0f / (sqrtf(b1) + 1e-8f);
    float w2 = 1.0f / (sqrtf(b2) + 1e-8f);
    float ws = (w0 + w1) + w2;
    size_t o = ((size_t)b * NPOINTS + p) * 3;
    L.idxo[o] = i0; L.idxo[o + 1] = i1; L.idxo[o + 2] = i2;
    L.wo[o] = w0 / ws; L.wo[o + 1] = w1 / ws; L.wo[o + 2] = w2 / ws;
  }
}

// ---------------- Gather-interp (float4) + per-block channel partial sums ----------------
template <int C, int BDIM>
__global__ __launch_bounds__(BDIM) void interp_kernel(
    const float* __restrict__ voxf, const int* __restrict__ idxo,
    const float* __restrict__ wo, float* __restrict__ out,
    float* __restrict__ psum, float* __restrict__ psq, int Nv)
{
  constexpr int C4 = C / 4;
  constexpr int R  = BDIM / C4;
  const int b = blockIdx.y, blk = blockIdx.x;
  const int tid = threadIdx.x;
  const int r = tid / C4, c4 = tid - r * C4;
  const float4* fb = (const float4*)(voxf + (size_t)b * Nv * C);
  float4* ob = (float4*)(out + (size_t)b * NPOINTS * C);
  const int p0 = blk * NPB;

  float4 s = make_float4(0, 0, 0, 0), q = make_float4(0, 0, 0, 0);
  for (int p = p0 + r; p < p0 + NPB; p += R) {
    size_t pg = ((size_t)b * NPOINTS + p) * 3;
    int   ia = idxo[pg], ib = idxo[pg + 1], ic = idxo[pg + 2];
    float wa = wo[pg],   wb = wo[pg + 1],   wc = wo[pg + 2];
    float4 fa = fb[(size_t)ia * C4 + c4];
    float4 f2 = fb[(size_t)ib * C4 + c4];
    float4 fc = fb[(size_t)ic * C4 + c4];
    float4 o;
    o.x = wa * fa.x + wb * f2.x + wc * fc.x;
    o.y = wa * fa.y + wb * f2.y + wc * fc.y;
    o.z = wa * fa.z + wb * f2.z + wc * fc.z;
    o.w = wa * fa.w + wb * f2.w + wc * fc.w;
    ob[(size_t)p * C4 + c4] = o;
    s.x += o.x; s.y += o.y; s.z += o.z; s.w += o.w;
    q.x += o.x * o.x; q.y += o.y * o.y; q.z += o.z * o.z; q.w += o.w * o.w;
  }

  __shared__ float4 ls[BDIM];
  ls[tid] = s;
  __syncthreads();
  if (r == 0) {
    float4 tot = s;
    #pragma unroll
    for (int rr = 1; rr < R; ++rr) {
      float4 v = ls[c4 + rr * C4];
      tot.x += v.x; tot.y += v.y; tot.z += v.z; tot.w += v.w;
    }
    ((float4*)psum)[((size_t)b * NBLK + blk) * C4 + c4] = tot;
  }
  __syncthreads();
  ls[tid] = q;
  __syncthreads();
  if (r == 0) {
    float4 tot = q;
    #pragma unroll
    for (int rr = 1; rr < R; ++rr) {
      float4 v = ls[c4 + rr * C4];
      tot.x += v.x; tot.y += v.y; tot.z += v.z; tot.w += v.w;
    }
    ((float4*)psq)[((size_t)b * NBLK + blk) * C4 + c4] = tot;
  }
}

// ---------------- BN stats (parallel reduce over NBLK partials) ----------------
__global__ __launch_bounds__(256) void bn_stats_kernel(
    const float* __restrict__ psum, const float* __restrict__ psq,
    const float* __restrict__ gamma, const float* __restrict__ beta,
    float* __restrict__ scale, float* __restrict__ shift, int C, float invN)
{
  const int c = blockIdx.x, b = blockIdx.y, t = threadIdx.x;
  float s = 0.f, q = 0.f;
  for (int k = t; k < NBLK; k += 256) {
    s += psum[((size_t)b * NBLK + k) * C + c];
    q += psq[((size_t)b * NBLK + k) * C + c];
  }
  __shared__ float ss[256], qs[256];
  ss[t] = s; qs[t] = q;
  __syncthreads();
  for (int o = 128; o > 0; o >>= 1) {
    if (t < o) { ss[t] += ss[t + o]; qs[t] += qs[t + o]; }
    __syncthreads();
  }
  if (t == 0) {
    float mu  = ss[0] * invN;
    float var = fmaxf(qs[0] * invN - mu * mu, 0.f);
    float sc  = gamma[c] * rsqrtf(var + 1e-5f);
    scale[b * C + c] = sc;
    shift[b * C + c] = beta[c] - mu * sc;
  }
}

// ---------------- In-place normalize (float4) ----------------
__global__ __launch_bounds__(256) void bn_apply_kernel(
    float* __restrict__ out, const float* __restrict__ scale,
    const float* __restrict__ shift, int C, int NpC)
{
  const int e = blockIdx.x * 256 + threadIdx.x;
  const int npc4 = NpC >> 2, c4n = C >> 2;
  const int b = e / npc4;
  const int rem = e - b * npc4;
  const int c4 = rem % c4n;
  float4 v  = ((float4*)out)[e];
  float4 sc = ((const float4*)scale)[b * c4n + c4];
  float4 sh = ((const float4*)shift)[b * c4n + c4];
  v.x = fmaf(v.x, sc.x, sh.x);
  v.y = fmaf(v.y, sc.y, sh.y);
  v.z = fmaf(v.z, sc.z, sh.z);
  v.w = fmaf(v.w, sc.w, sh.w);
  ((float4*)out)[e] = v;
}

// ---------------- Host launch ----------------
extern "C" void kernel_launch(void* const* d_in, const int* in_sizes, int n_in,
                              void* d_out, int out_size, void* d_ws, size_t ws_size,
                              hipStream_t stream)
{
  const float* ptc = (const float*)d_in[0];
  static const int    Cs[4]     = {256, 128, 96, 96};
  static const int    Nvs[4]    = {2048, 6144, 16384, 32768};
  static const int    Gs[4]     = {10, 14, 18, 22};   // ~2-3 voxels/cell
  static const size_t outOff[4] = {0, 16777216, 25165824, 31457280};

  // ---- workspace carve ----
  size_t off = 0;
  auto carve = [&](size_t bytes) {
    off = (off + 255) & ~(size_t)255;
    size_t o = off; off += bytes; return o;
  };
  char* w = (char*)d_ws;

  int nc[NJOB];
  for (int l = 0; l < 4; ++l) nc[l] = Gs[l] * Gs[l] * Gs[l];
  nc[4] = PCELLS;
  int Ns[NJOB] = {Nvs[0], Nvs[1], Nvs[2], Nvs[3], NPOINTS};
  int Gj[NJOB] = {Gs[0], Gs[1], Gs[2], Gs[3], PG};

  // contiguous counter block (zeroed with one launch)
  int totcnt = 0;
  for (int j = 0; j < NJOB; ++j) totcnt += nc[j];
  int* cntbase = (int*)(w + carve((size_t)NBATCH * totcnt * 4));

  float4* sortedj[NJOB]; int* cntj[NJOB]; int* sttj[NJOB]; int* curj[NJOB];
  {
    int acc = 0;
    for (int j = 0; j < NJOB; ++j) {
      cntj[j] = cntbase + (size_t)NBATCH * acc;
      acc += nc[j];
    }
  }
  for (int j = 0; j < NJOB; ++j) {
    sortedj[j] = (float4*)(w + carve((size_t)NBATCH * Ns[j] * 16));
    sttj[j]    = (int*)   (w + carve((size_t)NBATCH * (nc[j] + 1) * 4));
    curj[j]    = (int*)   (w + carve((size_t)NBATCH * nc[j] * 4));
  }
  int*   idxo  = (int*)  (w + carve((size_t)NLEV * NBATCH * NPOINTS * 3 * 4));
  float* wo    = (float*)(w + carve((size_t)NLEV * NBATCH * NPOINTS * 3 * 4));
  float* psum  = (float*)(w + carve((size_t)NBATCH * NBLK * 256 * 4));
  float* psq   = (float*)(w + carve((size_t)NBATCH * NBLK * 256 * 4));
  float* scale = (float*)(w + carve((size_t)NBATCH * 256 * 4));
  float* shift = (float*)(w + carve((size_t)NBATCH * 256 * 4));

  BinParams bp;
  for (int j = 0; j < NJOB; ++j) {
    BinJob& J = bp.job[j];
    J.coords = (j < 4) ? (const float*)d_in[1 + 4 * j] : ptc;
    J.cnt = cntj[j]; J.start = sttj[j]; J.cur = curj[j]; J.sorted = sortedj[j];
    J.G = Gj[j]; J.ncells = nc[j]; J.N = Ns[j];
    J.invh = Gj[j] / 50.0f;
  }

  Params prm;
  for (int l = 0; l < 4; ++l) {
    Level& L = prm.lv[l];
    L.sorted = sortedj[l]; L.start = sttj[l];
    L.idxo = idxo + (size_t)l * NBATCH * NPOINTS * 3;
    L.wo   = wo   + (size_t)l * NBATCH * NPOINTS * 3;
    L.G = Gs[l]; L.ncells = nc[l]; L.Nv = Nvs[l];
    L.h = 50.0f / Gs[l]; L.invh = Gs[l] / 50.0f;
  }

  // ---- fused binning ----
  const int zn = NBATCH * totcnt;
  zero_kernel<<<(zn + 255) / 256, 256, 0, stream>>>(cntbase, zn);
  count_kernel<<<dim3((NPOINTS + 255) / 256, NBATCH, NJOB), 256, 0, stream>>>(bp);
  scan_kernel<<<dim3(NBATCH, NJOB), 1024, 0, stream>>>(bp);
  scatter_kernel<<<dim3((NPOINTS + 255) / 256, NBATCH, NJOB), 256, 0, stream>>>(bp);

  // ---- exact 3-NN query: 16 lanes per point ----
  query_kernel<<<dim3(NPOINTS / 16, NLEV, NBATCH), 256, 0, stream>>>(sortedj[4], prm);

  // ---- per-level: interp(+stats) -> BN stats -> in-place apply ----
  for (int l = 0; l < 4; ++l) {
    const float* voxf  = (const float*)d_in[2 + 4 * l];
    const float* gamma = (const float*)d_in[3 + 4 * l];
    const float* beta  = (const float*)d_in[4 + 4 * l];
    const int C = Cs[l], Nv = Nvs[l];
    float* outl = (float*)d_out + outOff[l];
    const int* idl = idxo + (size_t)l * NBATCH * NPOINTS * 3;
    const float* wl = wo  + (size_t)l * NBATCH * NPOINTS * 3;

    if (C == 256)
      interp_kernel<256, 256><<<dim3(NBLK, NBATCH), 256, 0, stream>>>(
          voxf, idl, wl, outl, psum, psq, Nv);
    else if (C == 128)
      interp_kernel<128, 256><<<dim3(NBLK, NBATCH), 256, 0, stream>>>(
          voxf, idl, wl, outl, psum, psq, Nv);
    else
      interp_kernel<96, 240><<<dim3(NBLK, NBATCH), 240, 0, stream>>>(
          voxf, idl, wl, outl, psum, psq, Nv);

    bn_stats_kernel<<<dim3(C, NBATCH), 256, 0, stream>>>(
        psum, psq, gamma, beta, scale, shift, C, 1.0f / NPOINTS);

    const int n4 = NBATCH * NPOINTS * C / 4;
    bn_apply_kernel<<<n4 / 256, 256, 0, stream>>>(
        (float*)outl, scale, shift, C, NPOINTS * C);
  }
}

// Round 11
// 391.899 us; speedup vs baseline: 3.8295x; 1.3133x over previous
//
#include <hip/hip_runtime.h>
#include <cfloat>
#include <climits>
#include <cstdint>

#define NPOINTS 32768
#define NBATCH  2
#define NLEV    4
#define NJOB    5          // 4 voxel levels + 1 point sort
#define PG      16         // point-sort grid
#define PCELLS  (PG*PG*PG)
#define NPB     128
#define NBLK    (NPOINTS / NPB)   // 256

struct BinJob {
  const float* coords;   // [B, N, 3]
  int* cnt; int* start; int* cur;
  float4* sorted;        // [B, N] {x,y,z,bitcast(idx)} in bin order
  int G, ncells, N;
  float invh;
};
struct BinParams { BinJob job[NJOB]; };

struct Level {
  const float4* sorted;  // [B, Nv] coords in bin order, .w = bit-cast original idx
  const int*    start;   // [B, ncells+1]
  int*          idxo;    // [B*Np*3], original-id indexed
  float*        wo;      // [B*Np*3]
  int G, ncells, Nv;
  float h, invh;
};
struct Params { Level lv[NLEV]; };

struct ApplyParams {
  const float* scale[NLEV];
  const float* shift[NLEV];
};

__device__ __forceinline__ int cell1d(float x, float invh, int G) {
  int c = (int)(x * invh);
  return min(max(c, 0), G - 1);
}

__global__ __launch_bounds__(256) void zero_kernel(int* __restrict__ p, int n)
{
  int i = blockIdx.x * 256 + threadIdx.x;
  if (i < n) p[i] = 0;
}

// ---------------- fused bin counts (all jobs) ----------------
__global__ __launch_bounds__(256) void count_kernel(BinParams prm)
{
  const BinJob J = prm.job[blockIdx.z];
  int v = blockIdx.x * 256 + threadIdx.x;
  int b = blockIdx.y;
  if (v >= J.N) return;
  const float* p = J.coords + ((size_t)b * J.N + v) * 3;
  int cx = cell1d(p[0], J.invh, J.G), cy = cell1d(p[1], J.invh, J.G), cz = cell1d(p[2], J.invh, J.G);
  atomicAdd(&J.cnt[b * J.ncells + (cz * J.G + cy) * J.G + cx], 1);
}

// ---------------- fused exclusive scan (one block per batch x job) ----------------
__global__ __launch_bounds__(1024) void scan_kernel(BinParams prm)
{
  const BinJob J = prm.job[blockIdx.y];
  const int b = blockIdx.x, t = threadIdx.x;
  const int ncells = J.ncells;
  const int* c  = J.cnt + (size_t)b * ncells;
  int* st = J.start + (size_t)b * (ncells + 1);
  int* cu = J.cur + (size_t)b * ncells;
  __shared__ int part[1024];
  const int chunk = (ncells + 1023) / 1024;
  const int lo = t * chunk, hi = min(lo + chunk, ncells);
  int s = 0;
  for (int i = lo; i < hi; ++i) s += c[i];
  part[t] = s;
  __syncthreads();
  for (int off = 1; off < 1024; off <<= 1) {
    int v = (t >= off) ? part[t - off] : 0;
    __syncthreads();
    part[t] += v;
    __syncthreads();
  }
  int base = (t > 0) ? part[t - 1] : 0;
  for (int i = lo; i < hi; ++i) { st[i] = base; cu[i] = base; base += c[i]; }
  if (t == 1023) st[ncells] = part[1023];
}

// ---------------- fused scatter: packed coords+idx into bin order ----------------
__global__ __launch_bounds__(256) void scatter_kernel(BinParams prm)
{
  const BinJob J = prm.job[blockIdx.z];
  int v = blockIdx.x * 256 + threadIdx.x;
  int b = blockIdx.y;
  if (v >= J.N) return;
  const float* p = J.coords + ((size_t)b * J.N + v) * 3;
  float x = p[0], y = p[1], z = p[2];
  int cx = cell1d(x, J.invh, J.G), cy = cell1d(y, J.invh, J.G), cz = cell1d(z, J.invh, J.G);
  int pos = atomicAdd(&J.cur[b * J.ncells + (cz * J.G + cy) * J.G + cx], 1);
  J.sorted[(size_t)b * J.N + pos] = make_float4(x, y, z, __int_as_float(v));
}

// ---- Phase-1 query: hoisted 3x3x3 block, 4 lanes/point; certify-or-defer ----
__global__ __launch_bounds__(256) void phase1_kernel(
    const float4* __restrict__ psorted, Params prm,
    unsigned* __restrict__ taillist, int* __restrict__ tailcnt)
{
  const int l = blockIdx.y, b = blockIdx.z;
  const Level L = prm.lv[l];
  const int tid = threadIdx.x;
  const int q = tid & 3;                        // quad lane
  const int sp = blockIdx.x * 64 + (tid >> 2);  // sorted point slot
  float4 pt = psorted[(size_t)b * NPOINTS + sp];
  const float px = pt.x, py = pt.y, pz = pt.z;
  const int p = __float_as_int(pt.w);           // original point id
  const int G = L.G;
  const float h = L.h;

  const int cx = cell1d(px, L.invh, G);
  const int cy = cell1d(py, L.invh, G);
  const int cz = cell1d(pz, L.invh, G);
  const float fx = px - cx * h, fy = py - cy * h, fz = pz - cz * h;
  float m = fminf(fminf(fminf(fx, h - fx), fminf(fy, h - fy)), fminf(fz, h - fz));
  m = fmaxf(m, 0.f);

  const int* start     = L.start  + (size_t)b * (L.ncells + 1);
  const float4* sorted = L.sorted + (size_t)b * L.Nv;

  float b0 = FLT_MAX, b1 = FLT_MAX, b2 = FLT_MAX;
  int   i0 = INT_MAX, i1 = INT_MAX, i2 = INT_MAX;

  auto ins = [&](float d2, int vi) {             // lex (d2, idx) — proven
    if (d2 < b2 || (d2 == b2 && vi < i2)) {
      if (d2 < b1 || (d2 == b1 && vi < i1)) {
        b2 = b1; i2 = i1;
        if (d2 < b0 || (d2 == b0 && vi < i0)) { b1 = b0; i1 = i0; b0 = d2; i0 = vi; }
        else                                  { b1 = d2; i1 = vi; }
      } else { b2 = d2; i2 = vi; }
    }
  };
  auto cand = [&](int k) {
    float4 vv = sorted[k];
    int vi = __float_as_int(vv.w);
    // exact reference arithmetic: individually-rounded squares, (x2+y2)+z2
    float dx = px - vv.x, dy = py - vv.y, dz = pz - vv.z;
    float d2 = __fadd_rn(__fadd_rn(__fmul_rn(dx, dx), __fmul_rn(dy, dy)),
                         __fmul_rn(dz, dz));
    ins(d2, vi);
  };

  // hoisted 3x3x3 block (R7-proven): 18 independent bound loads, then 9 quad-split scans
  {
    const int x0 = max(cx - 1, 0), x1 = min(cx + 1, G - 1);
    int ks9[9], ke9[9];
    #pragma unroll
    for (int i = 0; i < 9; ++i) {
      const int dz = i / 3 - 1, dy = i % 3 - 1;
      const int iz = cz + dz, iy = cy + dy;
      const bool ok = (iz >= 0) && (iz < G) && (iy >= 0) && (iy < G);
      const int row = (iz * G + iy) * G;
      const int sa = ok ? (row + x0) : 0;
      const int sb = ok ? (row + x1 + 1) : 0;
      int a = start[sa], e = start[sb];
      if (!ok) { a = 0; e = 0; }
      ks9[i] = a; ke9[i] = e;
    }
    #pragma unroll
    for (int i = 0; i < 9; ++i)
      for (int k = ks9[i] + q; k < ke9[i]; k += 4) cand(k);
  }

  // quad merge (R7-proven): after this the triple is quad-uniform and exact for the block
  #pragma unroll
  for (int mask = 1; mask <= 2; mask <<= 1) {
    float c0 = __shfl_xor(b0, mask), c1 = __shfl_xor(b1, mask), c2 = __shfl_xor(b2, mask);
    int   j0 = __shfl_xor(i0, mask), j1 = __shfl_xor(i1, mask), j2 = __shfl_xor(i2, mask);
    ins(c0, j0); ins(c1, j1); ins(c2, j2);
  }

  // exact containment: every voxel outside the block is at distance >= h+m
  float dmin = h + m;
  bool contained = (dmin * dmin * 0.99999f > b2);

  if (q == 0) {
    if (contained) {
      float w0 = 1.0f / (sqrtf(b0) + 1e-8f);
      float w1 = 1.0f / (sqrtf(b1) + 1e-8f);
      float w2 = 1.0f / (sqrtf(b2) + 1e-8f);
      float ws = (w0 + w1) + w2;
      size_t o = ((size_t)b * NPOINTS + p) * 3;
      L.idxo[o] = i0; L.idxo[o + 1] = i1; L.idxo[o + 2] = i2;
      L.wo[o] = w0 / ws; L.wo[o + 1] = w1 / ws; L.wo[o + 2] = w2 / ws;
    } else {
      int slot = atomicAdd(tailcnt, 1);
      taillist[slot] = (unsigned)sp | ((unsigned)l << 15) | ((unsigned)b << 17);
    }
  }
}

// ---- Tail query: R5-proven full ring walk for deferred points (compacted list) ----
__global__ __launch_bounds__(256) void tail_kernel(
    const float4* __restrict__ psorted, Params prm,
    const unsigned* __restrict__ taillist, const int* __restrict__ tailcnt)
{
  const int tid = threadIdx.x;
  const int q = tid & 3;
  const int ent = blockIdx.x * 64 + (tid >> 2);
  const int n = *tailcnt;
  if (ent >= n) return;

  unsigned e = taillist[ent];
  const int sp = e & 0x7fff;
  const int l  = (e >> 15) & 3;
  const int b  = (e >> 17) & 1;
  const Level L = prm.lv[l];
  float4 pt = psorted[(size_t)b * NPOINTS + sp];
  const float px = pt.x, py = pt.y, pz = pt.z;
  const int p = __float_as_int(pt.w);
  const int G = L.G;
  const float h = L.h;

  const int cx = cell1d(px, L.invh, G);
  const int cy = cell1d(py, L.invh, G);
  const int cz = cell1d(pz, L.invh, G);
  const float fx = px - cx * h, fy = py - cy * h, fz = pz - cz * h;
  float m = fminf(fminf(fminf(fx, h - fx), fminf(fy, h - fy)), fminf(fz, h - fz));
  m = fmaxf(m, 0.f);

  const int* start     = L.start  + (size_t)b * (L.ncells + 1);
  const float4* sorted = L.sorted + (size_t)b * L.Nv;

  float b0 = FLT_MAX, b1 = FLT_MAX, b2 = FLT_MAX;
  int   i0 = INT_MAX, i1 = INT_MAX, i2 = INT_MAX;

  auto ins = [&](float d2, int vi) {
    if (d2 < b2 || (d2 == b2 && vi < i2)) {
      if (d2 < b1 || (d2 == b1 && vi < i1)) {
        b2 = b1; i2 = i1;
        if (d2 < b0 || (d2 == b0 && vi < i0)) { b1 = b0; i1 = i0; b0 = d2; i0 = vi; }
        else                                  { b1 = d2; i1 = vi; }
      } else { b2 = d2; i2 = vi; }
    }
  };
  auto cand = [&](int k) {
    float4 vv = sorted[k];
    int vi = __float_as_int(vv.w);
    // exact reference arithmetic: individually-rounded squares, (x2+y2)+z2
    float dx = px - vv.x, dy = py - vv.y, dz = pz - vv.z;
    float d2 = __fadd_rn(__fadd_rn(__fmul_rn(dx, dx), __fmul_rn(dy, dy)),
                         __fmul_rn(dz, dz));
    ins(d2, vi);
  };
  auto scan_range = [&](int ks, int ke) {
    for (int k = ks + q; k < ke; k += 4) cand(k);
  };

  const int rmax = max(max(cx, G - 1 - cx), max(max(cy, G - 1 - cy), max(cz, G - 1 - cz)));
  for (int rho = 0; rho <= rmax; ++rho) {
    if (rho >= 1) {
      // quad-wide valid bound: union's true b2 <= min over lanes of local b2 (R5-proven)
      float bm = fminf(b2, __shfl_xor(b2, 1));
      bm = fminf(bm, __shfl_xor(bm, 2));
      float dmin = fmaxf((rho - 1) * h + m, 0.f);
      if (dmin * dmin * 0.99999f > bm) break;   // conservative exact-prune bound
    }
    const int z0 = max(cz - rho, 0), z1 = min(cz + rho, G - 1);
    const int y0 = max(cy - rho, 0), y1 = min(cy + rho, G - 1);
    for (int iz = z0; iz <= z1; ++iz) {
      const int adz = abs(iz - cz);
      for (int iy = y0; iy <= y1; ++iy) {
        const int ady = max(adz, abs(iy - cy));
        const int row = (iz * G + iy) * G;
        if (ady == rho) {
          const int xa = max(cx - rho, 0), xb = min(cx + rho, G - 1);
          scan_range(start[row + xa], start[row + xb + 1]);
        } else {
          const int xl = cx - rho, xr = cx + rho;
          if (xl >= 0)     scan_range(start[row + xl], start[row + xl + 1]);
          if (xr <= G - 1) scan_range(start[row + xr], start[row + xr + 1]);
        }
      }
    }
  }

  // merge the 4 lanes' sorted triples (deterministic, lex (d2, idx))
  #pragma unroll
  for (int mask = 1; mask <= 2; mask <<= 1) {
    float c0 = __shfl_xor(b0, mask), c1 = __shfl_xor(b1, mask), c2 = __shfl_xor(b2, mask);
    int   j0 = __shfl_xor(i0, mask), j1 = __shfl_xor(i1, mask), j2 = __shfl_xor(i2, mask);
    ins(c0, j0); ins(c1, j1); ins(c2, j2);
  }

  if (q == 0) {
    float w0 = 1.0f / (sqrtf(b0) + 1e-8f);
    float w1 = 1.0f / (sqrtf(b1) + 1e-8f);
    float w2 = 1.0f / (sqrtf(b2) + 1e-8f);
    float ws = (w0 + w1) + w2;
    size_t o = ((size_t)b * NPOINTS + p) * 3;
    L.idxo[o] = i0; L.idxo[o + 1] = i1; L.idxo[o + 2] = i2;
    L.wo[o] = w0 / ws; L.wo[o + 1] = w1 / ws; L.wo[o + 2] = w2 / ws;
  }
}

// ---------------- Gather-interp (float4) + per-block channel partial sums ----------------
template <int C, int BDIM>
__global__ __launch_bounds__(BDIM) void interp_kernel(
    const float* __restrict__ voxf, const int* __restrict__ idxo,
    const float* __restrict__ wo, float* __restrict__ out,
    float* __restrict__ psum, float* __restrict__ psq, int Nv)
{
  constexpr int C4 = C / 4;
  constexpr int R  = BDIM / C4;
  const int b = blockIdx.y, blk = blockIdx.x;
  const int tid = threadIdx.x;
  const int r = tid / C4, c4 = tid - r * C4;
  const float4* fb = (const float4*)(voxf + (size_t)b * Nv * C);
  float4* ob = (float4*)(out + (size_t)b * NPOINTS * C);
  const int p0 = blk * NPB;

  float4 s = make_float4(0, 0, 0, 0), q = make_float4(0, 0, 0, 0);
  for (int p = p0 + r; p < p0 + NPB; p += R) {
    size_t pg = ((size_t)b * NPOINTS + p) * 3;
    int   ia = idxo[pg], ib = idxo[pg + 1], ic = idxo[pg + 2];
    float wa = wo[pg],   wb = wo[pg + 1],   wc = wo[pg + 2];
    float4 fa = fb[(size_t)ia * C4 + c4];
    float4 f2 = fb[(size_t)ib * C4 + c4];
    float4 fc = fb[(size_t)ic * C4 + c4];
    float4 o;
    o.x = wa * fa.x + wb * f2.x + wc * fc.x;
    o.y = wa * fa.y + wb * f2.y + wc * fc.y;
    o.z = wa * fa.z + wb * f2.z + wc * fc.z;
    o.w = wa * fa.w + wb * f2.w + wc * fc.w;
    ob[(size_t)p * C4 + c4] = o;
    s.x += o.x; s.y += o.y; s.z += o.z; s.w += o.w;
    q.x += o.x * o.x; q.y += o.y * o.y; q.z += o.z * o.z; q.w += o.w * o.w;
  }

  __shared__ float4 ls[BDIM];
  ls[tid] = s;
  __syncthreads();
  if (r == 0) {
    float4 tot = s;
    #pragma unroll
    for (int rr = 1; rr < R; ++rr) {
      float4 v = ls[c4 + rr * C4];
      tot.x += v.x; tot.y += v.y; tot.z += v.z; tot.w += v.w;
    }
    ((float4*)psum)[((size_t)b * NBLK + blk) * C4 + c4] = tot;
  }
  __syncthreads();
  ls[tid] = q;
  __syncthreads();
  if (r == 0) {
    float4 tot = q;
    #pragma unroll
    for (int rr = 1; rr < R; ++rr) {
      float4 v = ls[c4 + rr * C4];
      tot.x += v.x; tot.y += v.y; tot.z += v.z; tot.w += v.w;
    }
    ((float4*)psq)[((size_t)b * NBLK + blk) * C4 + c4] = tot;
  }
}

// ---------------- BN stats (parallel reduce over NBLK partials) ----------------
__global__ __launch_bounds__(256) void bn_stats_kernel(
    const float* __restrict__ psum, const float* __restrict__ psq,
    const float* __restrict__ gamma, const float* __restrict__ beta,
    float* __restrict__ scale, float* __restrict__ shift, int C, float invN)
{
  const int c = blockIdx.x, b = blockIdx.y, t = threadIdx.x;
  float s = 0.f, q = 0.f;
  for (int k = t; k < NBLK; k += 256) {
    s += psum[((size_t)b * NBLK + k) * C + c];
    q += psq[((size_t)b * NBLK + k) * C + c];
  }
  __shared__ float ss[256], qs[256];
  ss[t] = s; qs[t] = q;
  __syncthreads();
  for (int o = 128; o > 0; o >>= 1) {
    if (t < o) { ss[t] += ss[t + o]; qs[t] += qs[t + o]; }
    __syncthreads();
  }
  if (t == 0) {
    float mu  = ss[0] * invN;
    float var = fmaxf(qs[0] * invN - mu * mu, 0.f);
    float sc  = gamma[c] * rsqrtf(var + 1e-5f);
    scale[b * C + c] = sc;
    shift[b * C + c] = beta[c] - mu * sc;
  }
}

// ---------------- Fused in-place normalize across all 4 levels (float4) ----------------
// float4-unit level offsets: l1=4194304, l2=2097152, l3=l4=1572864
#define O1 4194304
#define O2 6291456
#define O3 7864320
__global__ __launch_bounds__(256) void bn_apply_all_kernel(
    float* __restrict__ out, ApplyParams ap)
{
  const int e = blockIdx.x * 256 + threadIdx.x;   // global float4 index
  int l, base, C4;
  if (e < O1)      { l = 0; base = 0;  C4 = 64; }
  else if (e < O2) { l = 1; base = O1; C4 = 32; }
  else if (e < O3) { l = 2; base = O2; C4 = 24; }
  else             { l = 3; base = O3; C4 = 24; }
  const int local = e - base;
  const int npc4 = NPOINTS * C4;
  const int b = local / npc4;
  const int rem = local - b * npc4;
  const int c4 = rem % C4;
  float4 v  = ((float4*)out)[e];
  float4 sc = ((const float4*)ap.scale[l])[b * C4 + c4];
  float4 sh = ((const float4*)ap.shift[l])[b * C4 + c4];
  v.x = fmaf(v.x, sc.x, sh.x);
  v.y = fmaf(v.y, sc.y, sh.y);
  v.z = fmaf(v.z, sc.z, sh.z);
  v.w = fmaf(v.w, sc.w, sh.w);
  ((float4*)out)[e] = v;
}

// ---------------- Host launch ----------------
extern "C" void kernel_launch(void* const* d_in, const int* in_sizes, int n_in,
                              void* d_out, int out_size, void* d_ws, size_t ws_size,
                              hipStream_t stream)
{
  const float* ptc = (const float*)d_in[0];
  static const int    Cs[4]     = {256, 128, 96, 96};
  static const int    Nvs[4]    = {2048, 6144, 16384, 32768};
  static const int    Gs[4]     = {10, 14, 18, 22};   // ~2-3 voxels/cell (R5-proven)
  static const size_t outOff[4] = {0, 16777216, 25165824, 31457280};

  // ---- workspace carve ----
  size_t off = 0;
  auto carve = [&](size_t bytes) {
    off = (off + 255) & ~(size_t)255;
    size_t o = off; off += bytes; return o;
  };
  char* w = (char*)d_ws;

  int nc[NJOB];
  for (int l = 0; l < 4; ++l) nc[l] = Gs[l] * Gs[l] * Gs[l];
  nc[4] = PCELLS;
  int Ns[NJOB] = {Nvs[0], Nvs[1], Nvs[2], Nvs[3], NPOINTS};
  int Gj[NJOB] = {Gs[0], Gs[1], Gs[2], Gs[3], PG};

  // contiguous counter block + tail counter (zeroed with one launch)
  int totcnt = 0;
  for (int j = 0; j < NJOB; ++j) totcnt += nc[j];
  int* cntbase = (int*)(w + carve(((size_t)NBATCH * totcnt + 1) * 4));
  int* tailcnt = cntbase + (size_t)NBATCH * totcnt;

  float4* sortedj[NJOB]; int* cntj[NJOB]; int* sttj[NJOB]; int* curj[NJOB];
  {
    int acc = 0;
    for (int j = 0; j < NJOB; ++j) {
      cntj[j] = cntbase + (size_t)NBATCH * acc;
      acc += nc[j];
    }
  }
  for (int j = 0; j < NJOB; ++j) {
    sortedj[j] = (float4*)(w + carve((size_t)NBATCH * Ns[j] * 16));
    sttj[j]    = (int*)   (w + carve((size_t)NBATCH * (nc[j] + 1) * 4));
    curj[j]    = (int*)   (w + carve((size_t)NBATCH * nc[j] * 4));
  }
  int*      idxo   = (int*)     (w + carve((size_t)NLEV * NBATCH * NPOINTS * 3 * 4));
  float*    wo     = (float*)   (w + carve((size_t)NLEV * NBATCH * NPOINTS * 3 * 4));
  unsigned* taillist = (unsigned*)(w + carve((size_t)NLEV * NBATCH * NPOINTS * 4));
  float*    psum   = (float*)   (w + carve((size_t)NBATCH * NBLK * 256 * 4));
  float*    psq    = (float*)   (w + carve((size_t)NBATCH * NBLK * 256 * 4));
  float*    scale4[4]; float* shift4[4];
  for (int l = 0; l < 4; ++l) {
    scale4[l] = (float*)(w + carve((size_t)NBATCH * 256 * 4));
    shift4[l] = (float*)(w + carve((size_t)NBATCH * 256 * 4));
  }

  BinParams bp;
  for (int j = 0; j < NJOB; ++j) {
    BinJob& J = bp.job[j];
    J.coords = (j < 4) ? (const float*)d_in[1 + 4 * j] : ptc;
    J.cnt = cntj[j]; J.start = sttj[j]; J.cur = curj[j]; J.sorted = sortedj[j];
    J.G = Gj[j]; J.ncells = nc[j]; J.N = Ns[j];
    J.invh = Gj[j] / 50.0f;
  }

  Params prm;
  for (int l = 0; l < 4; ++l) {
    Level& L = prm.lv[l];
    L.sorted = sortedj[l]; L.start = sttj[l];
    L.idxo = idxo + (size_t)l * NBATCH * NPOINTS * 3;
    L.wo   = wo   + (size_t)l * NBATCH * NPOINTS * 3;
    L.G = Gs[l]; L.ncells = nc[l]; L.Nv = Nvs[l];
    L.h = 50.0f / Gs[l]; L.invh = Gs[l] / 50.0f;
  }

  ApplyParams ap;
  for (int l = 0; l < 4; ++l) { ap.scale[l] = scale4[l]; ap.shift[l] = shift4[l]; }

  // ---- fused binning ----
  const int zn = NBATCH * totcnt + 1;
  zero_kernel<<<(zn + 255) / 256, 256, 0, stream>>>(cntbase, zn);
  count_kernel<<<dim3((NPOINTS + 255) / 256, NBATCH, NJOB), 256, 0, stream>>>(bp);
  scan_kernel<<<dim3(NBATCH, NJOB), 1024, 0, stream>>>(bp);
  scatter_kernel<<<dim3((NPOINTS + 255) / 256, NBATCH, NJOB), 256, 0, stream>>>(bp);

  // ---- query: phase-1 certify-or-defer, then tail ring-walk on compacted list ----
  phase1_kernel<<<dim3(NPOINTS / 64, NLEV, NBATCH), 256, 0, stream>>>(
      sortedj[4], prm, taillist, tailcnt);
  tail_kernel<<<(NLEV * NBATCH * NPOINTS) / 64, 256, 0, stream>>>(
      sortedj[4], prm, taillist, tailcnt);

  // ---- per-level: interp(+stats) -> BN stats; then one fused apply ----
  for (int l = 0; l < 4; ++l) {
    const float* voxf  = (const float*)d_in[2 + 4 * l];
    const float* gamma = (const float*)d_in[3 + 4 * l];
    const float* beta  = (const float*)d_in[4 + 4 * l];
    const int C = Cs[l], Nv = Nvs[l];
    float* outl = (float*)d_out + outOff[l];
    const int* idl = idxo + (size_t)l * NBATCH * NPOINTS * 3;
    const float* wl = wo  + (size_t)l * NBATCH * NPOINTS * 3;

    if (C == 256)
      interp_kernel<256, 256><<<dim3(NBLK, NBATCH), 256, 0, stream>>>(
          voxf, idl, wl, outl, psum, psq, Nv);
    else if (C == 128)
      interp_kernel<128, 256><<<dim3(NBLK, NBATCH), 256, 0, stream>>>(
          voxf, idl, wl, outl, psum, psq, Nv);
    else
      interp_kernel<96, 240><<<dim3(NBLK, NBATCH), 240, 0, stream>>>(
          voxf, idl, wl, outl, psum, psq, Nv);

    bn_stats_kernel<<<dim3(C, NBATCH), 256, 0, stream>>>(
        psum, psq, gamma, beta, scale4[l], shift4[l], C, 1.0f / NPOINTS);
  }

  const int n4tot = 9437184;   // total float4 elements across levels
  bn_apply_all_kernel<<<n4tot / 256, 256, 0, stream>>>((float*)d_out, ap);
}